// Round 10
// baseline (246.330 us; speedup 1.0000x reference)
//
#include <hip/hip_runtime.h>
#include <hip/hip_bf16.h>

// HyConv round 10: round-9 design, compile fix — __builtin_nontemporal_load needs a
// native vector type, not HIP's float4 class; use ext_vector_type(4) float.
// memset(ctr) -> build_k -> gemm_k -> phase1_pull -> phase2_pull

#define BB 4
#define NN 10000
#define MM 10000
#define EE 160000
#define CC 128
#define BM (BB * MM)   // 40000 hyperedge buckets
#define BN (BB * NN)   // 40000 node buckets
#define NCOPY 8
#define CAPX 16        // per-copy bucket cap; per-copy deg ~ Poisson(2), P[>=17]~5e-11

typedef unsigned short u16;
typedef float f4 __attribute__((ext_vector_type(4)));  // native vec for nontemporal IO
using bf16 = __hip_bfloat16;

// ---------------- build: one thread per edge, XCD-local copy = blockIdx & 7 ----------
__global__ __launch_bounds__(256) void build_k(const int* __restrict__ H,
                                               int* __restrict__ ctr,
                                               u16* __restrict__ srcA,
                                               u16* __restrict__ srcB) {
    const int g = blockIdx.x * 256 + threadIdx.x;  // 0..639,999
    if (g >= BB * EE) return;
    const int cp = blockIdx.x & 7;
    const int b = g / EE, e = g - b * EE;
    const int nd = H[b * 2 * EE + e];
    const int he = H[b * 2 * EE + EE + e];
    const int bktA = b * MM + he;
    const int s = atomicAdd(&ctr[cp * (BM + BN) + bktA], 1);
    if (s < CAPX) srcA[((size_t)cp * BM + bktA) * CAPX + s] = (u16)nd;
    const int bktB = b * NN + nd;
    const int q = atomicAdd(&ctr[cp * (BM + BN) + BM + bktB], 1);
    if (q < CAPX) srcB[((size_t)cp * BN + bktB) * CAPX + q] = (u16)he;
}

// ---------------- gemm: 32 rows x 128 cols / block; nontemporal x-load + xt-store ----
__global__ __launch_bounds__(256) void gemm_k(const float* __restrict__ x,
                                              const float* __restrict__ theta,
                                              u16* __restrict__ xt) {
    __shared__ float sTh[64 * 128];  // 32 KB
    __shared__ float sX[32 * 128];   // 16 KB
    const int tid = threadIdx.x;
    const int row0 = blockIdx.x * 32;
    {
        const f4* src = (const f4*)&x[row0 * 128];
        f4* dst = (f4*)sX;
#pragma unroll
        for (int i = 0; i < 4; ++i)
            dst[tid + 256 * i] = __builtin_nontemporal_load(src + tid + 256 * i);
    }
    const int cg2 = (tid & 63) * 2;
    const int rg = tid >> 6;
    float ax[8], ay[8];
#pragma unroll
    for (int r = 0; r < 8; ++r) { ax[r] = 0.f; ay[r] = 0.f; }

    for (int half = 0; half < 2; ++half) {
        __syncthreads();
        {
            const float4* src = (const float4*)&theta[half * 64 * 128];
            float4* dst = (float4*)sTh;
#pragma unroll
            for (int i = 0; i < 8; ++i) dst[tid + 256 * i] = src[tid + 256 * i];
        }
        __syncthreads();
#pragma unroll
        for (int k4 = 0; k4 < 16; ++k4) {
            const int kk = 4 * k4;
            const float2 t0 = *(const float2*)&sTh[(kk + 0) * 128 + cg2];
            const float2 t1 = *(const float2*)&sTh[(kk + 1) * 128 + cg2];
            const float2 t2 = *(const float2*)&sTh[(kk + 2) * 128 + cg2];
            const float2 t3 = *(const float2*)&sTh[(kk + 3) * 128 + cg2];
#pragma unroll
            for (int r = 0; r < 8; ++r) {
                const float4 xv =
                    *(const float4*)&sX[(rg * 8 + r) * 128 + half * 64 + kk];
                ax[r] = fmaf(xv.x, t0.x, ax[r]); ay[r] = fmaf(xv.x, t0.y, ay[r]);
                ax[r] = fmaf(xv.y, t1.x, ax[r]); ay[r] = fmaf(xv.y, t1.y, ay[r]);
                ax[r] = fmaf(xv.z, t2.x, ax[r]); ay[r] = fmaf(xv.z, t2.y, ay[r]);
                ax[r] = fmaf(xv.w, t3.x, ax[r]); ay[r] = fmaf(xv.w, t3.y, ay[r]);
            }
        }
    }
#pragma unroll
    for (int r = 0; r < 8; ++r) {
        bf16 hx = __float2bfloat16(ax[r]);
        bf16 hy = __float2bfloat16(ay[r]);
        const unsigned pk =
            (unsigned)*(u16*)&hx | ((unsigned)*(u16*)&hy << 16);
        __builtin_nontemporal_store(
            pk, (unsigned*)(xt + (size_t)(row0 + rg * 8 + r) * CC + cg2));
    }
}

// ---------------- merge 8 copy-lists into per-wave LDS (vectorized) ----------------
__device__ __forceinline__ int merge_lists(const int* __restrict__ ctr,
                                           const u16* __restrict__ src,
                                           int side_off, int Bx, int wid, int lane,
                                           u16* __restrict__ buf) {
    int cnt = 0;
    if (lane < NCOPY) {
        cnt = ctr[lane * (BM + BN) + side_off + wid];
        cnt = cnt > CAPX ? CAPX : cnt;
    }
    int pre = cnt;  // inclusive prefix over lanes 0..7
#pragma unroll
    for (int d = 1; d < 8; d <<= 1) {
        const int o = __shfl_up(pre, d, 64);
        if (lane >= d) pre += o;
    }
    const int base = pre - cnt;
    int total = __shfl(pre, 7, 64);
    if (lane < NCOPY) {
        const u16* lst = src + ((size_t)lane * Bx + wid) * CAPX;
        const uint4 lo = *(const uint4*)lst;        // entries 0..7 (unconditional)
        const uint4 hi = *(const uint4*)(lst + 8);  // entries 8..15
        const unsigned ev[8] = {lo.x, lo.y, lo.z, lo.w, hi.x, hi.y, hi.z, hi.w};
#pragma unroll
        for (int j = 0; j < CAPX; ++j) {  // predicated compaction, static extracts
            if (j < cnt) buf[base + j] = (u16)(ev[j >> 1] >> ((j & 1) * 16));
        }
    }
    __syncthreads();
    return total > 128 ? 128 : total;
}

__device__ __forceinline__ float ldbf(const u16* __restrict__ p, int idx) {
    return __uint_as_float(((unsigned)p[(size_t)idx * CC]) << 16);
}

// ---------------- phase1: x_edge = segment-mean(xt); group=(b,half)=bi&7 -------------
// grid 20000 = 8 groups x 2500 blocks; wave = one (bucket, half); lane = one channel.
__global__ __launch_bounds__(256) void phase1_pull(const u16* __restrict__ xt,
                                                   const int* __restrict__ ctr,
                                                   const u16* __restrict__ srcA,
                                                   u16* __restrict__ x_edge) {
    __shared__ __align__(16) u16 buf[4 * 128];
    const int bi = blockIdx.x;
    const int grp = bi & 7;                    // XCD-local group (heuristic: XCD = bi%8)
    const int b = grp >> 1, half = grp & 1;
    const int w = threadIdx.x >> 6, lane = threadIdx.x & 63;
    const int wid = b * MM + (bi >> 3) * 4 + w;  // bucket
    u16* wbuf = &buf[w * 128];
    const int total = merge_lists(ctr, srcA, 0, BM, wid, lane, wbuf);

    const u16* basep = xt + (size_t)b * NN * CC + half * 64 + lane;
    float s = 0.f;
    int i = 0;
    for (; i + 8 <= total; i += 8) {
        const uint4 pk = *(const uint4*)&wbuf[i];
        s += ldbf(basep, pk.x & 0xffff); s += ldbf(basep, pk.x >> 16);
        s += ldbf(basep, pk.y & 0xffff); s += ldbf(basep, pk.y >> 16);
        s += ldbf(basep, pk.z & 0xffff); s += ldbf(basep, pk.z >> 16);
        s += ldbf(basep, pk.w & 0xffff); s += ldbf(basep, pk.w >> 16);
    }
    for (; i < total; ++i) s += ldbf(basep, wbuf[i]);
    const float wgt = total ? 1.0f / (float)total : 0.f;
    const bf16 h = __float2bfloat16(s * wgt);
    __builtin_nontemporal_store(
        *(const u16*)&h, x_edge + (size_t)wid * CC + half * 64 + lane);
}

// ---------------- phase2: out = segment-mean(x_edge) + bias; same partition ----------
__global__ __launch_bounds__(256) void phase2_pull(const u16* __restrict__ x_edge,
                                                   const int* __restrict__ ctr,
                                                   const u16* __restrict__ srcB,
                                                   const float* __restrict__ bias,
                                                   float* __restrict__ out) {
    __shared__ __align__(16) u16 buf[4 * 128];
    const int bi = blockIdx.x;
    const int grp = bi & 7;
    const int b = grp >> 1, half = grp & 1;
    const int w = threadIdx.x >> 6, lane = threadIdx.x & 63;
    const int wid = b * NN + (bi >> 3) * 4 + w;
    u16* wbuf = &buf[w * 128];
    const int total = merge_lists(ctr, srcB, BM, BN, wid, lane, wbuf);

    const u16* basep = x_edge + (size_t)b * MM * CC + half * 64 + lane;
    float s = 0.f;
    int i = 0;
    for (; i + 8 <= total; i += 8) {
        const uint4 pk = *(const uint4*)&wbuf[i];
        s += ldbf(basep, pk.x & 0xffff); s += ldbf(basep, pk.x >> 16);
        s += ldbf(basep, pk.y & 0xffff); s += ldbf(basep, pk.y >> 16);
        s += ldbf(basep, pk.z & 0xffff); s += ldbf(basep, pk.z >> 16);
        s += ldbf(basep, pk.w & 0xffff); s += ldbf(basep, pk.w >> 16);
    }
    for (; i < total; ++i) s += ldbf(basep, wbuf[i]);
    const float wgt = total ? 1.0f / (float)total : 0.f;
    const float o = s * wgt + bias[half * 64 + lane];
    __builtin_nontemporal_store(o, out + (size_t)wid * CC + half * 64 + lane);
}

extern "C" void kernel_launch(void* const* d_in, const int* in_sizes, int n_in,
                              void* d_out, int out_size, void* d_ws, size_t ws_size,
                              hipStream_t stream) {
    const float* x = (const float*)d_in[0];
    const int* H = (const int*)d_in[1];
    const float* theta = (const float*)d_in[2];
    const float* bias = (const float*)d_in[3];
    float* out = (float*)d_out;

    // workspace (~43.5 MB): xt(bf16) | x_edge(bf16) | ctr(8 copies) | srcA | srcB
    u16* xt = (u16*)d_ws;                                     // 10.24 MB
    u16* x_edge = xt + (size_t)BB * NN * CC;                  // 10.24 MB
    int* ctr = (int*)(x_edge + (size_t)BB * MM * CC);         // 2.56 MB
    u16* srcA = (u16*)(ctr + NCOPY * (BM + BN));              // 10.24 MB
    u16* srcB = srcA + (size_t)NCOPY * BM * CAPX;             // 10.24 MB

    (void)hipMemsetAsync(ctr, 0, (size_t)NCOPY * (BM + BN) * sizeof(int), stream);

    build_k<<<2500, 256, 0, stream>>>(H, ctr, srcA, srcB);
    gemm_k<<<1250, 256, 0, stream>>>(x, theta, xt);
    phase1_pull<<<20000, 256, 0, stream>>>(xt, ctr, srcA, x_edge);
    phase2_pull<<<20000, 256, 0, stream>>>(x_edge, ctr, srcB, bias, out);
}

// Round 11
// 214.998 us; speedup vs baseline: 1.1457x; 1.1457x over previous
//
#include <hip/hip_runtime.h>
#include <hip/hip_bf16.h>

// HyConv round 11: back to r8 skeleton (best), with
//  - single-copy CAP=64 bucket lists (r10 showed 8-copy never cut writeback; halves footprint)
//  - fused build||gemm (1:2) kept (r10 showed unfusing loses overlap)
//  - phases: pair-split half-wave gathers (2 rows per VMEM instr, 16 rows in flight),
//    clamped+masked unconditional chunks (no serial tail), no merge needed.
// memset(ctr 320KB) -> build_gemm -> phase1_pull -> phase2_pull

#define BB 4
#define NN 10000
#define MM 10000
#define EE 160000
#define CC 128
#define BM (BB * MM)   // 40000 hyperedge buckets
#define BN (BB * NN)   // 40000 node buckets
#define CAP 64         // bucket capacity (validated exact vs CSR in round 3/4)

typedef unsigned short u16;
using bf16 = __hip_bfloat16;

// ---------------- fused: gemm (bi%3==0) || build (bi%3!=0) ----------------
// grid = 3750: 1250 gemm blocks (32 rows each), 2500 build blocks (640k edges).
__global__ __launch_bounds__(256) void build_gemm_k(const int* __restrict__ H,
                                                    int* __restrict__ ctr,
                                                    u16* __restrict__ srcA,
                                                    u16* __restrict__ srcB,
                                                    const float* __restrict__ x,
                                                    const float* __restrict__ theta,
                                                    u16* __restrict__ xt) {
    __shared__ float sTh[64 * 128];  // 32 KB
    __shared__ float sX[32 * 128];   // 16 KB
    const int bi = blockIdx.x;

    if (bi % 3 != 0) {
        // ---- build: one thread per edge, single copy ----
        const int j = bi - bi / 3 - 1;               // 0..2499 among build blocks
        const int g = j * 256 + threadIdx.x;         // 0..639,999
        if (g >= BB * EE) return;
        const int b = g / EE, e = g - b * EE;
        const int nd = H[b * 2 * EE + e];
        const int he = H[b * 2 * EE + EE + e];
        const int bktA = b * MM + he;
        const int s = atomicAdd(&ctr[bktA], 1);
        if (s < CAP) srcA[(size_t)bktA * CAP + s] = (u16)nd;
        const int bktB = b * NN + nd;
        const int q = atomicAdd(&ctr[BM + bktB], 1);
        if (q < CAP) srcB[(size_t)bktB * CAP + q] = (u16)he;
        return;
    }

    // ---- gemm: 32 rows x 128 cols per block; thread = 8 rows x 2 cols ----
    const int tid = threadIdx.x;
    const int row0 = (bi / 3) * 32;  // rows 0..39968
    {
        const float4* src = (const float4*)&x[row0 * 128];
        float4* dst = (float4*)sX;
#pragma unroll
        for (int i = 0; i < 4; ++i) dst[tid + 256 * i] = src[tid + 256 * i];
    }
    const int cg2 = (tid & 63) * 2;
    const int rg = tid >> 6;
    float ax[8], ay[8];
#pragma unroll
    for (int r = 0; r < 8; ++r) { ax[r] = 0.f; ay[r] = 0.f; }

    for (int half = 0; half < 2; ++half) {
        __syncthreads();
        {
            const float4* src = (const float4*)&theta[half * 64 * 128];
            float4* dst = (float4*)sTh;
#pragma unroll
            for (int i = 0; i < 8; ++i) dst[tid + 256 * i] = src[tid + 256 * i];
        }
        __syncthreads();
#pragma unroll
        for (int k4 = 0; k4 < 16; ++k4) {
            const int kk = 4 * k4;
            const float2 t0 = *(const float2*)&sTh[(kk + 0) * 128 + cg2];
            const float2 t1 = *(const float2*)&sTh[(kk + 1) * 128 + cg2];
            const float2 t2 = *(const float2*)&sTh[(kk + 2) * 128 + cg2];
            const float2 t3 = *(const float2*)&sTh[(kk + 3) * 128 + cg2];
#pragma unroll
            for (int r = 0; r < 8; ++r) {
                const float4 xv =
                    *(const float4*)&sX[(rg * 8 + r) * 128 + half * 64 + kk];
                ax[r] = fmaf(xv.x, t0.x, ax[r]); ay[r] = fmaf(xv.x, t0.y, ay[r]);
                ax[r] = fmaf(xv.y, t1.x, ax[r]); ay[r] = fmaf(xv.y, t1.y, ay[r]);
                ax[r] = fmaf(xv.z, t2.x, ax[r]); ay[r] = fmaf(xv.z, t2.y, ay[r]);
                ax[r] = fmaf(xv.w, t3.x, ax[r]); ay[r] = fmaf(xv.w, t3.y, ay[r]);
            }
        }
    }
#pragma unroll
    for (int r = 0; r < 8; ++r) {
        bf16 hx = __float2bfloat16(ax[r]);
        bf16 hy = __float2bfloat16(ay[r]);
        const unsigned pk = (unsigned)*(u16*)&hx | ((unsigned)*(u16*)&hy << 16);
        *(unsigned*)(xt + (size_t)(row0 + rg * 8 + r) * CC + cg2) = pk;
    }
}

__device__ __forceinline__ float bflo(unsigned r) { return __uint_as_float(r << 16); }
__device__ __forceinline__ float bfhi(unsigned r) {
    return __uint_as_float(r & 0xffff0000u);
}

// ---------------- shared gather: pair-split half-wave, clamped chunks --------------
// lane = 32*half + cl; entry (2k+half) of a chunk lives in packed word k, half selects
// lo/hi. Each gather instr covers TWO rows (8 B = 4 channels per lane).
__device__ __forceinline__ float4 bucket_mean_ps(const u16* __restrict__ base,
                                                 const u16* __restrict__ lst, int cnt,
                                                 int half) {
    float4 acc = {0.f, 0.f, 0.f, 0.f};
    const int nch = (cnt + 15) >> 4;  // 16-entry chunks
    const int hsh = half * 16;
    for (int c = 0; c < nch; ++c) {
        const int i0 = c * 16;
        const uint4 wa = *(const uint4*)&lst[i0];      // entries i0..i0+7
        const uint4 wb = *(const uint4*)&lst[i0 + 8];  // entries i0+8..i0+15
        const unsigned wrd[8] = {wa.x, wa.y, wa.z, wa.w, wb.x, wb.y, wb.z, wb.w};
#pragma unroll
        for (int k = 0; k < 8; ++k) {
            const int e = i0 + 2 * k + half;
            const int idx = (int)((wrd[k] >> hsh) & 0x3fffu);  // mask keeps stale in-ws
            const uint2 raw = *(const uint2*)&base[(size_t)idx * CC];  // unconditional
            if (e < cnt) {  // predicated accumulate only
                acc.x += bflo(raw.x); acc.y += bfhi(raw.x);
                acc.z += bflo(raw.y); acc.w += bfhi(raw.y);
            }
        }
    }
    // cross-half combine: lanes 0..31 end with full sums
    acc.x += __shfl_down(acc.x, 32);
    acc.y += __shfl_down(acc.y, 32);
    acc.z += __shfl_down(acc.z, 32);
    acc.w += __shfl_down(acc.w, 32);
    return acc;
}

// ---------------- phase1: x_edge[bkt] = mean over incident nodes of xt --------------
__global__ __launch_bounds__(256) void phase1_pull(const u16* __restrict__ xt,
                                                   const int* __restrict__ ctr,
                                                   const u16* __restrict__ srcA,
                                                   u16* __restrict__ x_edge) {
    const int wid = (blockIdx.x * 256 + threadIdx.x) >> 6;  // bucket = b*MM+he
    const int lane = threadIdx.x & 63;
    const int half = lane >> 5, cl = lane & 31;
    int cnt = ctr[wid];
    cnt = cnt > CAP ? CAP : cnt;
    const u16* lst = srcA + (size_t)wid * CAP;
    const u16* base = xt + (size_t)(wid / MM) * NN * CC + cl * 4;
    const float4 acc = bucket_mean_ps(base, lst, cnt, half);
    if (lane < 32) {
        const float w = cnt ? 1.0f / (float)cnt : 0.f;
        bf16 h0 = __float2bfloat16(acc.x * w);
        bf16 h1 = __float2bfloat16(acc.y * w);
        bf16 h2 = __float2bfloat16(acc.z * w);
        bf16 h3 = __float2bfloat16(acc.w * w);
        uint2 pk;
        pk.x = (unsigned)*(u16*)&h0 | ((unsigned)*(u16*)&h1 << 16);
        pk.y = (unsigned)*(u16*)&h2 | ((unsigned)*(u16*)&h3 << 16);
        *(uint2*)&x_edge[(size_t)wid * CC + cl * 4] = pk;
    }
}

// ---------------- phase2: out[bkt] = mean over incident hyperedges + bias -----------
__global__ __launch_bounds__(256) void phase2_pull(const u16* __restrict__ x_edge,
                                                   const int* __restrict__ ctr,
                                                   const u16* __restrict__ srcB,
                                                   const float* __restrict__ bias,
                                                   float* __restrict__ out) {
    const int wid = (blockIdx.x * 256 + threadIdx.x) >> 6;  // bucket = b*NN+nd
    const int lane = threadIdx.x & 63;
    const int half = lane >> 5, cl = lane & 31;
    int cnt = ctr[BM + wid];
    cnt = cnt > CAP ? CAP : cnt;
    const u16* lst = srcB + (size_t)wid * CAP;
    const u16* base = x_edge + (size_t)(wid / NN) * MM * CC + cl * 4;
    const float4 acc = bucket_mean_ps(base, lst, cnt, half);
    if (lane < 32) {
        const float w = cnt ? 1.0f / (float)cnt : 0.f;
        const float4 bv = *(const float4*)&bias[cl * 4];
        float4 o;
        o.x = acc.x * w + bv.x;
        o.y = acc.y * w + bv.y;
        o.z = acc.z * w + bv.z;
        o.w = acc.w * w + bv.w;
        *(float4*)&out[(size_t)wid * CC + cl * 4] = o;
    }
}

extern "C" void kernel_launch(void* const* d_in, const int* in_sizes, int n_in,
                              void* d_out, int out_size, void* d_ws, size_t ws_size,
                              hipStream_t stream) {
    const float* x = (const float*)d_in[0];
    const int* H = (const int*)d_in[1];
    const float* theta = (const float*)d_in[2];
    const float* bias = (const float*)d_in[3];
    float* out = (float*)d_out;

    // workspace (~31 MB): xt(bf16) | x_edge(bf16) | ctr | srcA | srcB
    u16* xt = (u16*)d_ws;                              // 10.24 MB
    u16* x_edge = xt + (size_t)BB * NN * CC;           // 10.24 MB
    int* ctr = (int*)(x_edge + (size_t)BB * MM * CC);  // 320 KB
    u16* srcA = (u16*)(ctr + (BM + BN));               // 5.12 MB
    u16* srcB = srcA + (size_t)BM * CAP;               // 5.12 MB

    (void)hipMemsetAsync(ctr, 0, (size_t)(BM + BN) * sizeof(int), stream);

    build_gemm_k<<<3750, 256, 0, stream>>>(H, ctr, srcA, srcB, x, theta, xt);
    phase1_pull<<<BM / 4, 256, 0, stream>>>(xt, ctr, srcA, x_edge);
    phase2_pull<<<BN / 4, 256, 0, stream>>>(x_edge, ctr, srcB, bias, out);
}

// Round 12
// 207.306 us; speedup vs baseline: 1.1882x; 1.0371x over previous
//
#include <hip/hip_runtime.h>
#include <hip/hip_bf16.h>

// HyConv round 12: physically-XCD-bound bucket copies (cp = HW_REG_XCC_ID, not the
// weak blockIdx&7 heuristic) -> each src line dirtied by exactly ONE per-XCD L2 ->
// writeback ~= footprint once. Phases: vectorized LDS merge of 8 copies + pair-split
// chunked gather (2 rows / VMEM instr). Fused build||gemm 1:2 kept.
// memset(ctr) -> build_gemm -> phase1_pull -> phase2_pull

#define BB 4
#define NN 10000
#define MM 10000
#define EE 160000
#define CC 128
#define BM (BB * MM)   // 40000 hyperedge buckets
#define BN (BB * NN)   // 40000 node buckets
#define NCOPY 8
#define CAPX 16        // per-XCD bucket cap; per-XCD deg ~ Poisson(2), P[>16]~1e-11

typedef unsigned short u16;
using bf16 = __hip_bfloat16;

// s_getreg SIMM16 = (size-1)<<11 | offset<<6 | id ; HW_REG_XCC_ID = 20 (gfx940+)
#define XCC_ID_REG ((3 << 11) | (0 << 6) | 20)  // 4 bits, offset 0

// ---------------- fused: gemm (bi%3==0) || build (bi%3!=0) ----------------
// grid = 3750: 1250 gemm blocks (32 rows each), 2500 build blocks (640k edges).
__global__ __launch_bounds__(256) void build_gemm_k(const int* __restrict__ H,
                                                    int* __restrict__ ctr,
                                                    u16* __restrict__ srcA,
                                                    u16* __restrict__ srcB,
                                                    const float* __restrict__ x,
                                                    const float* __restrict__ theta,
                                                    u16* __restrict__ xt) {
    __shared__ float sTh[64 * 128];  // 32 KB
    __shared__ float sX[32 * 128];   // 16 KB
    const int bi = blockIdx.x;

    if (bi % 3 != 0) {
        // ---- build: one thread per edge; copy = PHYSICAL XCD id ----
        const int j = bi - bi / 3 - 1;               // 0..2499 among build blocks
        const int g = j * 256 + threadIdx.x;         // 0..639,999
        if (g >= BB * EE) return;
        const int cp = (int)(__builtin_amdgcn_s_getreg(XCC_ID_REG) & 7u);
        const int b = g / EE, e = g - b * EE;
        const int nd = H[b * 2 * EE + e];
        const int he = H[b * 2 * EE + EE + e];
        const int bktA = b * MM + he;
        const int s = atomicAdd(&ctr[cp * (BM + BN) + bktA], 1);
        if (s < CAPX) srcA[((size_t)cp * BM + bktA) * CAPX + s] = (u16)nd;
        const int bktB = b * NN + nd;
        const int q = atomicAdd(&ctr[cp * (BM + BN) + BM + bktB], 1);
        if (q < CAPX) srcB[((size_t)cp * BN + bktB) * CAPX + q] = (u16)he;
        return;
    }

    // ---- gemm: 32 rows x 128 cols per block; thread = 8 rows x 2 cols ----
    const int tid = threadIdx.x;
    const int row0 = (bi / 3) * 32;  // rows 0..39968
    {
        const float4* src = (const float4*)&x[row0 * 128];
        float4* dst = (float4*)sX;
#pragma unroll
        for (int i = 0; i < 4; ++i) dst[tid + 256 * i] = src[tid + 256 * i];
    }
    const int cg2 = (tid & 63) * 2;
    const int rg = tid >> 6;
    float ax[8], ay[8];
#pragma unroll
    for (int r = 0; r < 8; ++r) { ax[r] = 0.f; ay[r] = 0.f; }

    for (int half = 0; half < 2; ++half) {
        __syncthreads();
        {
            const float4* src = (const float4*)&theta[half * 64 * 128];
            float4* dst = (float4*)sTh;
#pragma unroll
            for (int i = 0; i < 8; ++i) dst[tid + 256 * i] = src[tid + 256 * i];
        }
        __syncthreads();
#pragma unroll
        for (int k4 = 0; k4 < 16; ++k4) {
            const int kk = 4 * k4;
            const float2 t0 = *(const float2*)&sTh[(kk + 0) * 128 + cg2];
            const float2 t1 = *(const float2*)&sTh[(kk + 1) * 128 + cg2];
            const float2 t2 = *(const float2*)&sTh[(kk + 2) * 128 + cg2];
            const float2 t3 = *(const float2*)&sTh[(kk + 3) * 128 + cg2];
#pragma unroll
            for (int r = 0; r < 8; ++r) {
                const float4 xv =
                    *(const float4*)&sX[(rg * 8 + r) * 128 + half * 64 + kk];
                ax[r] = fmaf(xv.x, t0.x, ax[r]); ay[r] = fmaf(xv.x, t0.y, ay[r]);
                ax[r] = fmaf(xv.y, t1.x, ax[r]); ay[r] = fmaf(xv.y, t1.y, ay[r]);
                ax[r] = fmaf(xv.z, t2.x, ax[r]); ay[r] = fmaf(xv.z, t2.y, ay[r]);
                ax[r] = fmaf(xv.w, t3.x, ax[r]); ay[r] = fmaf(xv.w, t3.y, ay[r]);
            }
        }
    }
#pragma unroll
    for (int r = 0; r < 8; ++r) {
        bf16 hx = __float2bfloat16(ax[r]);
        bf16 hy = __float2bfloat16(ay[r]);
        const unsigned pk = (unsigned)*(u16*)&hx | ((unsigned)*(u16*)&hy << 16);
        *(unsigned*)(xt + (size_t)(row0 + rg * 8 + r) * CC + cg2) = pk;
    }
}

// ---------------- merge 8 copy-lists into per-wave LDS (vectorized) ----------------
__device__ __forceinline__ int merge_lists(const int* __restrict__ ctr,
                                           const u16* __restrict__ src,
                                           int side_off, int Bx, int wid, int lane,
                                           u16* __restrict__ buf) {
    int cnt = 0;
    if (lane < NCOPY) {
        cnt = ctr[lane * (BM + BN) + side_off + wid];
        cnt = cnt > CAPX ? CAPX : cnt;
    }
    int pre = cnt;  // inclusive prefix over lanes 0..7
#pragma unroll
    for (int d = 1; d < 8; d <<= 1) {
        const int o = __shfl_up(pre, d, 64);
        if (lane >= d) pre += o;
    }
    const int base = pre - cnt;
    int total = __shfl(pre, 7, 64);
    if (lane < NCOPY) {
        const u16* lst = src + ((size_t)lane * Bx + wid) * CAPX;
        const uint4 lo = *(const uint4*)lst;        // entries 0..7 (unconditional)
        const uint4 hi = *(const uint4*)(lst + 8);  // entries 8..15
        const unsigned ev[8] = {lo.x, lo.y, lo.z, lo.w, hi.x, hi.y, hi.z, hi.w};
#pragma unroll
        for (int j = 0; j < CAPX; ++j) {  // predicated compaction, static extracts
            if (j < cnt) buf[base + j] = (u16)(ev[j >> 1] >> ((j & 1) * 16));
        }
    }
    __syncthreads();
    return total > 128 ? 128 : total;
}

__device__ __forceinline__ float bflo(unsigned r) { return __uint_as_float(r << 16); }
__device__ __forceinline__ float bfhi(unsigned r) {
    return __uint_as_float(r & 0xffff0000u);
}

// ---------------- pair-split chunked gather over merged LDS list --------------------
// lane = 32*half + cl; each VMEM instr fetches TWO rows (8 B = 4 channels / lane).
__device__ __forceinline__ float4 gather_ps(const u16* __restrict__ base,
                                            const u16* __restrict__ lst, int total,
                                            int half) {
    float4 acc = {0.f, 0.f, 0.f, 0.f};
    const int nch = (total + 15) >> 4;  // 16-entry chunks
    const int hsh = half * 16;
    for (int c = 0; c < nch; ++c) {
        const int i0 = c * 16;
        const uint4 wa = *(const uint4*)&lst[i0];      // LDS b128 reads
        const uint4 wb = *(const uint4*)&lst[i0 + 8];
        const unsigned wrd[8] = {wa.x, wa.y, wa.z, wa.w, wb.x, wb.y, wb.z, wb.w};
#pragma unroll
        for (int k = 0; k < 8; ++k) {
            const int e = i0 + 2 * k + half;
            const int idx = (int)((wrd[k] >> hsh) & 0x3fffu);  // clamp keeps stale in-ws
            const uint2 raw = *(const uint2*)&base[(size_t)idx * CC];  // unconditional
            if (e < total) {  // predicated accumulate only
                acc.x += bflo(raw.x); acc.y += bfhi(raw.x);
                acc.z += bflo(raw.y); acc.w += bfhi(raw.y);
            }
        }
    }
    acc.x += __shfl_down(acc.x, 32);
    acc.y += __shfl_down(acc.y, 32);
    acc.z += __shfl_down(acc.z, 32);
    acc.w += __shfl_down(acc.w, 32);
    return acc;  // lanes 0..31 hold full sums
}

// ---------------- phase1: x_edge[bkt] = mean over incident nodes of xt --------------
__global__ __launch_bounds__(256) void phase1_pull(const u16* __restrict__ xt,
                                                   const int* __restrict__ ctr,
                                                   const u16* __restrict__ srcA,
                                                   u16* __restrict__ x_edge) {
    __shared__ __align__(16) u16 buf[4 * 128];
    const int wid = (blockIdx.x * 256 + threadIdx.x) >> 6;  // bucket = b*MM+he
    const int lane = threadIdx.x & 63;
    const int half = lane >> 5, cl = lane & 31;
    u16* wbuf = &buf[(threadIdx.x >> 6) * 128];
    const int total = merge_lists(ctr, srcA, 0, BM, wid, lane, wbuf);

    const u16* base = xt + (size_t)(wid / MM) * NN * CC + cl * 4;
    const float4 acc = gather_ps(base, wbuf, total, half);
    if (lane < 32) {
        const float w = total ? 1.0f / (float)total : 0.f;
        bf16 h0 = __float2bfloat16(acc.x * w);
        bf16 h1 = __float2bfloat16(acc.y * w);
        bf16 h2 = __float2bfloat16(acc.z * w);
        bf16 h3 = __float2bfloat16(acc.w * w);
        uint2 pk;
        pk.x = (unsigned)*(u16*)&h0 | ((unsigned)*(u16*)&h1 << 16);
        pk.y = (unsigned)*(u16*)&h2 | ((unsigned)*(u16*)&h3 << 16);
        *(uint2*)&x_edge[(size_t)wid * CC + cl * 4] = pk;
    }
}

// ---------------- phase2: out[bkt] = mean over incident hyperedges + bias -----------
__global__ __launch_bounds__(256) void phase2_pull(const u16* __restrict__ x_edge,
                                                   const int* __restrict__ ctr,
                                                   const u16* __restrict__ srcB,
                                                   const float* __restrict__ bias,
                                                   float* __restrict__ out) {
    __shared__ __align__(16) u16 buf[4 * 128];
    const int wid = (blockIdx.x * 256 + threadIdx.x) >> 6;  // bucket = b*NN+nd
    const int lane = threadIdx.x & 63;
    const int half = lane >> 5, cl = lane & 31;
    u16* wbuf = &buf[(threadIdx.x >> 6) * 128];
    const int total = merge_lists(ctr, srcB, BM, BN, wid, lane, wbuf);

    const u16* base = x_edge + (size_t)(wid / NN) * MM * CC + cl * 4;
    const float4 acc = gather_ps(base, wbuf, total, half);
    if (lane < 32) {
        const float w = total ? 1.0f / (float)total : 0.f;
        const float4 bv = *(const float4*)&bias[cl * 4];
        float4 o;
        o.x = acc.x * w + bv.x;
        o.y = acc.y * w + bv.y;
        o.z = acc.z * w + bv.z;
        o.w = acc.w * w + bv.w;
        *(float4*)&out[(size_t)wid * CC + cl * 4] = o;
    }
}

extern "C" void kernel_launch(void* const* d_in, const int* in_sizes, int n_in,
                              void* d_out, int out_size, void* d_ws, size_t ws_size,
                              hipStream_t stream) {
    const float* x = (const float*)d_in[0];
    const int* H = (const int*)d_in[1];
    const float* theta = (const float*)d_in[2];
    const float* bias = (const float*)d_in[3];
    float* out = (float*)d_out;

    // workspace (~43.5 MB): xt(bf16) | x_edge(bf16) | ctr(8 copies) | srcA | srcB
    u16* xt = (u16*)d_ws;                              // 10.24 MB
    u16* x_edge = xt + (size_t)BB * NN * CC;           // 10.24 MB
    int* ctr = (int*)(x_edge + (size_t)BB * MM * CC);  // 2.56 MB
    u16* srcA = (u16*)(ctr + NCOPY * (BM + BN));       // 10.24 MB
    u16* srcB = srcA + (size_t)NCOPY * BM * CAPX;      // 10.24 MB

    (void)hipMemsetAsync(ctr, 0, (size_t)NCOPY * (BM + BN) * sizeof(int), stream);

    build_gemm_k<<<3750, 256, 0, stream>>>(H, ctr, srcA, srcB, x, theta, xt);
    phase1_pull<<<BM / 4, 256, 0, stream>>>(xt, ctr, srcA, x_edge);
    phase2_pull<<<BN / 4, 256, 0, stream>>>(x_edge, ctr, srcB, bias, out);
}